// Round 9
// baseline (3520.819 us; speedup 1.0000x reference)
//
#include <hip/hip_runtime.h>
#include <cstddef>

#define BATCH 8
#define NPTS 8192
#define NFEAT 64
#define NPOINT 2048
#define NSAMPLE 32

// -- plain-rounded ops, contraction-proof (hipcc defaults -ffp-contract=fast;
//    asm blocks mul->fma fusion, matching numpy's non-FMA ufuncs)
__device__ __forceinline__ float sq_nc(float a) {
    float r = a * a;
    asm volatile("" : "+v"(r));
    return r;
}
__device__ __forceinline__ float mul_nc(float a, float b) {
    float r = a * b;
    asm volatile("" : "+v"(r));
    return r;
}

// ---------------------------------------------------------------------------
// FPS: one block per batch, 512 threads, 16 points/thread. UNCHANGED from R8
// (bit-exact plain-rounded distances; ballot-based wave argmax; one barrier).
// ---------------------------------------------------------------------------
__global__ __launch_bounds__(512) void fps_kernel(const float* __restrict__ xyz,
                                                  float* __restrict__ newxyz) {
    extern __shared__ float lds[];
    float* sx = lds;
    float* sy = lds + NPTS;
    float* sz = lds + 2 * NPTS;
    __shared__ alignas(16) unsigned long long redp[2][8];

    const int b = blockIdx.x;
    const int tid = threadIdx.x;
    const int lane = tid & 63;
    const int wid = tid >> 6;
    const float* xb = xyz + (size_t)b * NPTS * 3;

    for (int i = tid; i < NPTS; i += 512) {
        sx[i] = xb[i * 3 + 0];
        sy[i] = xb[i * 3 + 1];
        sz[i] = xb[i * 3 + 2];
    }
    __syncthreads();

    float mx[16], my_[16], mz[16], md[16];
    const int base = tid * 16;
#pragma unroll
    for (int j = 0; j < 16; ++j) {
        mx[j] = sx[base + j];
        my_[j] = sy[base + j];
        mz[j] = sz[base + j];
        md[j] = INFINITY;
    }

    if (tid == 0) {
        newxyz[(size_t)b * NPOINT * 3 + 0] = sx[0];
        newxyz[(size_t)b * NPOINT * 3 + 1] = sy[0];
        newxyz[(size_t)b * NPOINT * 3 + 2] = sz[0];
    }
    float xl = sx[0], yl = sy[0], zl = sz[0];
    int par = 0;

    for (int it = 1; it < NPOINT; ++it) {
        float bv = -1.0f;
        int bi = 0;
#pragma unroll
        for (int j = 0; j < 16; ++j) {
            float dx = mx[j] - xl;
            float dy = my_[j] - yl;
            float dz = mz[j] - zl;
            float d = (sq_nc(dx) + sq_nc(dy)) + sq_nc(dz);
            float m = fminf(md[j], d);
            md[j] = m;
            if (m > bv) { bv = m; bi = base + j; }
        }

        float wv = bv;
#pragma unroll
        for (int m = 1; m < 64; m <<= 1)
            wv = fmaxf(wv, __shfl_xor(wv, m, 64));
        unsigned long long msk = __ballot(bv == wv);
        int src = __builtin_ctzll(msk);          // lowest lane = smallest idx
        int wbi = __shfl(bi, src, 64);

        if (lane == 0)
            redp[par][wid] = ((unsigned long long)__float_as_uint(wv) << 32) |
                             (unsigned int)(~(unsigned int)wbi);
        __syncthreads();

        const ulonglong2* rp = (const ulonglong2*)redp[par];
        ulonglong2 r0 = rp[0], r1 = rp[1], r2 = rp[2], r3 = rp[3];
        unsigned long long m0 = (r0.x > r0.y) ? r0.x : r0.y;
        unsigned long long m1 = (r1.x > r1.y) ? r1.x : r1.y;
        unsigned long long m2 = (r2.x > r2.y) ? r2.x : r2.y;
        unsigned long long m3 = (r3.x > r3.y) ? r3.x : r3.y;
        m0 = (m1 > m0) ? m1 : m0;
        m2 = (m3 > m2) ? m3 : m2;
        m0 = (m2 > m0) ? m2 : m0;
        const int fi = (int)(~(unsigned int)m0);

        xl = sx[fi]; yl = sy[fi]; zl = sz[fi];
        if (tid == 0) {
            size_t o = (size_t)b * NPOINT * 3 + (size_t)it * 3;
            newxyz[o + 0] = xl;
            newxyz[o + 1] = yl;
            newxyz[o + 2] = zl;
        }
        par ^= 1;
    }
}

// ---------------------------------------------------------------------------
// Ball query. UNCHANGED from R8 (verified).
// ---------------------------------------------------------------------------
__global__ __launch_bounds__(64) void ball_kernel(const float* __restrict__ xyz,
                                                  const float* __restrict__ newxyz,
                                                  int* __restrict__ ballidx) {
    extern __shared__ float4 s4[];                       // 8192 float4 = 128KB
    const int b = blockIdx.y;
    const int s = blockIdx.x * 64 + threadIdx.x;
    const float* xb = xyz + (size_t)b * NPTS * 3;
    for (int i = threadIdx.x; i < NPTS; i += 64) {
        float x = xb[i * 3 + 0], y = xb[i * 3 + 1], z = xb[i * 3 + 2];
        float sq = (sq_nc(x) + sq_nc(y)) + sq_nc(z);
        s4[i] = make_float4(x, y, z, sq);
    }
    __syncthreads();

    const int sIdx = b * NPOINT + s;
    float cx = newxyz[(size_t)sIdx * 3 + 0];
    float cy = newxyz[(size_t)sIdx * 3 + 1];
    float cz = newxyz[(size_t)sIdx * 3 + 2];
    float cq = (sq_nc(cx) + sq_nc(cy)) + sq_nc(cz);

    int* ob = ballidx + (size_t)sIdx * NSAMPLE;
    int cnt = 0;
    int first = 0;
#pragma unroll 4
    for (int n = 0; n < NPTS; ++n) {
        float4 p = s4[n];
        float dot = __fmaf_rn(cz, p.z, __fmaf_rn(cy, p.y, __fmul_rn(cx, p.x)));
        float d2 = (cq + p.w) - mul_nc(2.0f, dot);
        if (d2 < 0.04f && cnt < NSAMPLE) {
            ob[cnt] = n;
            if (cnt == 0) first = n;
            ++cnt;
        }
    }
    for (int j = cnt; j < NSAMPLE; ++j) ob[j] = first;
}

// ---------------------------------------------------------------------------
// F1 precompute. UNCHANGED from R8.
// ---------------------------------------------------------------------------
__global__ __launch_bounds__(256) void f1_kernel(const float* __restrict__ features,
                                                 const float* __restrict__ W1,
                                                 float* __restrict__ F1) {
    const int lane = threadIdx.x & 63;
    const int chunk = threadIdx.x >> 6;                // 0..3
    const int blk = blockIdx.x;                        // 0..1023
    const int b = blk >> 7;
    const int n = ((blk & 127) << 6) | lane;
    const float* fb = features + (size_t)b * NFEAT * NPTS + n;
    const float* wbase = W1 + 3 * 64 + chunk * 16;

    float acc[16];
#pragma unroll
    for (int i = 0; i < 16; ++i) acc[i] = 0.0f;

#pragma unroll 4
    for (int cp = 0; cp < 64; ++cp) {
        float f = fb[(size_t)cp * NPTS];
        const float4* w = reinterpret_cast<const float4*>(wbase + (size_t)cp * 64);
#pragma unroll
        for (int c4 = 0; c4 < 4; ++c4) {
            float4 ww = w[c4];
            acc[c4 * 4 + 0] += f * ww.x;
            acc[c4 * 4 + 1] += f * ww.y;
            acc[c4 * 4 + 2] += f * ww.z;
            acc[c4 * 4 + 3] += f * ww.w;
        }
    }
    float* o = F1 + ((size_t)b * NPTS + n) * 64 + chunk * 16;
#pragma unroll
    for (int c4 = 0; c4 < 4; ++c4) {
        float4 v;
        v.x = acc[c4 * 4 + 0]; v.y = acc[c4 * 4 + 1];
        v.z = acc[c4 * 4 + 2]; v.w = acc[c4 * 4 + 3];
        *reinterpret_cast<float4*>(o + c4 * 4) = v;
    }
}

// ---------------------------------------------------------------------------
// Fused grouped-MLP + max-pool. 256 blocks (1/CU); each block stages all
// weights in LDS ONCE, then loops over 8 center-groups (8 centers x 32
// samples each). No barriers in the loop: hbuf is per-thread-column only,
// weight reads are wave-uniform broadcasts.
// ---------------------------------------------------------------------------
__global__ __launch_bounds__(256) void mlp_kernel(const float* __restrict__ xyz,
                                                  const float* __restrict__ W1,
                                                  const float* __restrict__ b1,
                                                  const float* __restrict__ W2,
                                                  const float* __restrict__ b2,
                                                  const float* __restrict__ W3,
                                                  const float* __restrict__ b3,
                                                  const float* __restrict__ F1,
                                                  const int* __restrict__ ballidx,
                                                  const float* __restrict__ newxyz,
                                                  float* __restrict__ outF) {
    extern __shared__ float smem[];
    float* hbuf = smem;                 // [64][256] = 16384
    float* w2s  = smem + 16384;         // 4096
    float* w3s  = w2s + 4096;           // 8192
    float* w1s  = w3s + 8192;           // 192
    float* b1s  = w1s + 192;            // 64
    float* b2s  = b1s + 64;             // 64
    float* b3s  = b2s + 64;             // 128  -> total 29120 floats = 116.5KB

    const int tid = threadIdx.x;
    const int k = tid & 31;
    const int g = tid >> 5;

    // ---- stage weights/biases once per block (coalesced)
    for (int i = tid; i < 4096; i += 256) w2s[i] = W2[i];
    for (int i = tid; i < 8192; i += 256) w3s[i] = W3[i];
    if (tid < 192) w1s[tid] = W1[tid];
    if (tid < 64)  { b1s[tid] = b1[tid]; b2s[tid] = b2[tid]; }
    if (tid < 128) b3s[tid] = b3[tid];
    __syncthreads();

#pragma unroll 1
    for (int it = 0; it < 8; ++it) {
        const int sIdx = blockIdx.x * 64 + it * 8 + g;   // 0 .. BATCH*NPOINT-1
        const int b = sIdx >> 11;
        const int s = sIdx & (NPOINT - 1);

        const int p = ballidx[(size_t)sIdx * NSAMPLE + k];
        const float* xb = xyz + (size_t)b * NPTS * 3;
        float rx = xb[p * 3 + 0] - newxyz[(size_t)sIdx * 3 + 0];
        float ry = xb[p * 3 + 1] - newxyz[(size_t)sIdx * 3 + 1];
        float rz = xb[p * 3 + 2] - newxyz[(size_t)sIdx * 3 + 2];

        // ---- layer 1 -> LDS column
        const float* f1p = F1 + ((size_t)b * NPTS + p) * 64;
#pragma unroll 4
        for (int c4 = 0; c4 < 16; ++c4) {
            float4 f  = *reinterpret_cast<const float4*>(f1p + c4 * 4);
            float4 wx = *reinterpret_cast<const float4*>(w1s + c4 * 4);
            float4 wy = *reinterpret_cast<const float4*>(w1s + 64 + c4 * 4);
            float4 wz = *reinterpret_cast<const float4*>(w1s + 128 + c4 * 4);
            float4 bb = *reinterpret_cast<const float4*>(b1s + c4 * 4);
            hbuf[(c4 * 4 + 0) * 256 + tid] = fmaxf(bb.x + f.x + rx * wx.x + ry * wy.x + rz * wz.x, 0.0f);
            hbuf[(c4 * 4 + 1) * 256 + tid] = fmaxf(bb.y + f.y + rx * wx.y + ry * wy.y + rz * wz.y, 0.0f);
            hbuf[(c4 * 4 + 2) * 256 + tid] = fmaxf(bb.z + f.z + rx * wx.z + ry * wy.z + rz * wz.z, 0.0f);
            hbuf[(c4 * 4 + 3) * 256 + tid] = fmaxf(bb.w + f.w + rx * wx.w + ry * wy.w + rz * wz.w, 0.0f);
        }

        // ---- layer 2: h2 in regs, h1 from LDS column, W2 via LDS broadcast
        float h2[64];
#pragma unroll
        for (int d4 = 0; d4 < 16; ++d4) {
            float4 bb = *reinterpret_cast<const float4*>(b2s + d4 * 4);
            h2[d4 * 4 + 0] = bb.x; h2[d4 * 4 + 1] = bb.y;
            h2[d4 * 4 + 2] = bb.z; h2[d4 * 4 + 3] = bb.w;
        }
#pragma unroll 4
        for (int c = 0; c < 64; ++c) {
            float a = hbuf[c * 256 + tid];
            const float4* w = reinterpret_cast<const float4*>(w2s + c * 64);
#pragma unroll
            for (int d4 = 0; d4 < 16; ++d4) {
                float4 ww = w[d4];
                h2[d4 * 4 + 0] += a * ww.x;
                h2[d4 * 4 + 1] += a * ww.y;
                h2[d4 * 4 + 2] += a * ww.z;
                h2[d4 * 4 + 3] += a * ww.w;
            }
        }
#pragma unroll
        for (int d = 0; d < 64; ++d) hbuf[d * 256 + tid] = fmaxf(h2[d], 0.0f);

        // ---- layer 3 + relu + max over 32 samples, 4 chunks of 32 channels
        const size_t obase = (size_t)b * 128 * NPOINT + s;
#pragma unroll 1
        for (int ch = 0; ch < 4; ++ch) {
            float acc[32];
#pragma unroll
            for (int j4 = 0; j4 < 8; ++j4) {
                float4 bb = *reinterpret_cast<const float4*>(b3s + ch * 32 + j4 * 4);
                acc[j4 * 4 + 0] = bb.x; acc[j4 * 4 + 1] = bb.y;
                acc[j4 * 4 + 2] = bb.z; acc[j4 * 4 + 3] = bb.w;
            }
#pragma unroll 4
            for (int c = 0; c < 64; ++c) {
                float a = hbuf[c * 256 + tid];
                const float4* w = reinterpret_cast<const float4*>(w3s + c * 128 + ch * 32);
#pragma unroll
                for (int j4 = 0; j4 < 8; ++j4) {
                    float4 ww = w[j4];
                    acc[j4 * 4 + 0] += a * ww.x;
                    acc[j4 * 4 + 1] += a * ww.y;
                    acc[j4 * 4 + 2] += a * ww.z;
                    acc[j4 * 4 + 3] += a * ww.w;
                }
            }
#pragma unroll
            for (int j = 0; j < 32; ++j) {
                float v = fmaxf(acc[j], 0.0f);
#pragma unroll
                for (int m = 16; m >= 1; m >>= 1) v = fmaxf(v, __shfl_xor(v, m, 64));
                acc[j] = v;
            }
            if (k == 0) {
#pragma unroll
                for (int j = 0; j < 32; ++j)
                    outF[obase + (size_t)(ch * 32 + j) * NPOINT] = acc[j];
            }
        }
    }
}

// ---------------------------------------------------------------------------
extern "C" void kernel_launch(void* const* d_in, const int* in_sizes, int n_in,
                              void* d_out, int out_size, void* d_ws, size_t ws_size,
                              hipStream_t stream) {
    const float* xyz      = (const float*)d_in[0];
    const float* features = (const float*)d_in[1];
    const float* W1       = (const float*)d_in[2];
    const float* b1       = (const float*)d_in[3];
    const float* W2       = (const float*)d_in[4];
    const float* b2       = (const float*)d_in[5];
    const float* W3       = (const float*)d_in[6];
    const float* b3       = (const float*)d_in[7];

    float* out_newxyz = (float*)d_out;                                  // B*NPOINT*3 f32
    float* out_feat   = (float*)d_out + (size_t)BATCH * NPOINT * 3;     // B*128*NPOINT f32

    // workspace: ballidx 2MB | F1 16.8MB
    int*   ballidx = (int*)d_ws;
    float* F1      = (float*)((char*)d_ws + (size_t)BATCH * NPOINT * NSAMPLE * 4);

    f1_kernel<<<1024, 256, 0, stream>>>(features, W1, F1);

    fps_kernel<<<BATCH, 512, 3 * NPTS * 4, stream>>>(xyz, out_newxyz);

    ball_kernel<<<dim3(NPOINT / 64, BATCH), 64, NPTS * 16, stream>>>(xyz, out_newxyz, ballidx);

    mlp_kernel<<<256, 256, 29120 * 4, stream>>>(
        xyz, W1, b1, W2, b2, W3, b3, F1, ballidx, out_newxyz, out_feat);
}

// Round 10
// 2868.152 us; speedup vs baseline: 1.2276x; 1.2276x over previous
//
#include <hip/hip_runtime.h>
#include <cstddef>

#define BATCH 8
#define NPTS 8192
#define NFEAT 64
#define NPOINT 2048
#define NSAMPLE 32

// -- plain-rounded ops, contraction-proof (hipcc defaults -ffp-contract=fast;
//    asm blocks mul->fma fusion, matching numpy's non-FMA ufuncs)
__device__ __forceinline__ float sq_nc(float a) {
    float r = a * a;
    asm volatile("" : "+v"(r));
    return r;
}
__device__ __forceinline__ float mul_nc(float a, float b) {
    float r = a * b;
    asm volatile("" : "+v"(r));
    return r;
}

// ---------------------------------------------------------------------------
// FPS: one block per batch, 512 threads, 16 points/thread.
// Bit-exact plain-rounded distances (verified R4-R9); ballot wave argmax;
// one barrier/iter. NEW vs R9: xyz packed float4 in LDS -> center gather is
// one ds_read_b128 instead of 3 b32 reads.
// ---------------------------------------------------------------------------
__global__ __launch_bounds__(512) void fps_kernel(const float* __restrict__ xyz,
                                                  float* __restrict__ newxyz) {
    extern __shared__ float4 sp[];                       // 8192 float4 = 128KB
    __shared__ alignas(16) unsigned long long redp[2][8];

    const int b = blockIdx.x;
    const int tid = threadIdx.x;
    const int lane = tid & 63;
    const int wid = tid >> 6;
    const float* xb = xyz + (size_t)b * NPTS * 3;

    for (int i = tid; i < NPTS; i += 512)
        sp[i] = make_float4(xb[i * 3 + 0], xb[i * 3 + 1], xb[i * 3 + 2], 0.0f);
    __syncthreads();

    float mx[16], my_[16], mz[16], md[16];
    const int base = tid * 16;
#pragma unroll
    for (int j = 0; j < 16; ++j) {
        float4 p = sp[base + j];
        mx[j] = p.x; my_[j] = p.y; mz[j] = p.z;
        md[j] = INFINITY;
    }

    float4 c0 = sp[0];
    if (tid == 0) {
        newxyz[(size_t)b * NPOINT * 3 + 0] = c0.x;
        newxyz[(size_t)b * NPOINT * 3 + 1] = c0.y;
        newxyz[(size_t)b * NPOINT * 3 + 2] = c0.z;
    }
    float xl = c0.x, yl = c0.y, zl = c0.z;
    int par = 0;

    for (int it = 1; it < NPOINT; ++it) {
        float bv = -1.0f;
        int bi = 0;
#pragma unroll
        for (int j = 0; j < 16; ++j) {
            float dx = mx[j] - xl;
            float dy = my_[j] - yl;
            float dz = mz[j] - zl;
            float d = (sq_nc(dx) + sq_nc(dy)) + sq_nc(dz);
            float m = fminf(md[j], d);
            md[j] = m;
            if (m > bv) { bv = m; bi = base + j; }
        }

        float wv = bv;
#pragma unroll
        for (int m = 1; m < 64; m <<= 1)
            wv = fmaxf(wv, __shfl_xor(wv, m, 64));
        unsigned long long msk = __ballot(bv == wv);
        int src = __builtin_ctzll(msk);          // lowest lane = smallest idx
        int wbi = __shfl(bi, src, 64);

        if (lane == 0)
            redp[par][wid] = ((unsigned long long)__float_as_uint(wv) << 32) |
                             (unsigned int)(~(unsigned int)wbi);
        __syncthreads();

        const ulonglong2* rp = (const ulonglong2*)redp[par];
        ulonglong2 r0 = rp[0], r1 = rp[1], r2 = rp[2], r3 = rp[3];
        unsigned long long m0 = (r0.x > r0.y) ? r0.x : r0.y;
        unsigned long long m1 = (r1.x > r1.y) ? r1.x : r1.y;
        unsigned long long m2 = (r2.x > r2.y) ? r2.x : r2.y;
        unsigned long long m3 = (r3.x > r3.y) ? r3.x : r3.y;
        m0 = (m1 > m0) ? m1 : m0;
        m2 = (m3 > m2) ? m3 : m2;
        m0 = (m2 > m0) ? m2 : m0;
        const int fi = (int)(~(unsigned int)m0);

        float4 cc = sp[fi];
        xl = cc.x; yl = cc.y; zl = cc.z;
        if (tid == 0) {
            size_t o = (size_t)b * NPOINT * 3 + (size_t)it * 3;
            newxyz[o + 0] = xl;
            newxyz[o + 1] = yl;
            newxyz[o + 2] = zl;
        }
        par ^= 1;
    }
}

// ---------------------------------------------------------------------------
// Ball query. UNCHANGED (verified R5-R9).
// ---------------------------------------------------------------------------
__global__ __launch_bounds__(64) void ball_kernel(const float* __restrict__ xyz,
                                                  const float* __restrict__ newxyz,
                                                  int* __restrict__ ballidx) {
    extern __shared__ float4 s4[];                       // 8192 float4 = 128KB
    const int b = blockIdx.y;
    const int s = blockIdx.x * 64 + threadIdx.x;
    const float* xb = xyz + (size_t)b * NPTS * 3;
    for (int i = threadIdx.x; i < NPTS; i += 64) {
        float x = xb[i * 3 + 0], y = xb[i * 3 + 1], z = xb[i * 3 + 2];
        float sq = (sq_nc(x) + sq_nc(y)) + sq_nc(z);
        s4[i] = make_float4(x, y, z, sq);
    }
    __syncthreads();

    const int sIdx = b * NPOINT + s;
    float cx = newxyz[(size_t)sIdx * 3 + 0];
    float cy = newxyz[(size_t)sIdx * 3 + 1];
    float cz = newxyz[(size_t)sIdx * 3 + 2];
    float cq = (sq_nc(cx) + sq_nc(cy)) + sq_nc(cz);

    int* ob = ballidx + (size_t)sIdx * NSAMPLE;
    int cnt = 0;
    int first = 0;
#pragma unroll 4
    for (int n = 0; n < NPTS; ++n) {
        float4 p = s4[n];
        float dot = __fmaf_rn(cz, p.z, __fmaf_rn(cy, p.y, __fmul_rn(cx, p.x)));
        float d2 = (cq + p.w) - mul_nc(2.0f, dot);
        if (d2 < 0.04f && cnt < NSAMPLE) {
            ob[cnt] = n;
            if (cnt == 0) first = n;
            ++cnt;
        }
    }
    for (int j = cnt; j < NSAMPLE; ++j) ob[j] = first;
}

// ---------------------------------------------------------------------------
// F1 precompute. UNCHANGED (R7).
// ---------------------------------------------------------------------------
__global__ __launch_bounds__(256) void f1_kernel(const float* __restrict__ features,
                                                 const float* __restrict__ W1,
                                                 float* __restrict__ F1) {
    const int lane = threadIdx.x & 63;
    const int chunk = threadIdx.x >> 6;                // 0..3
    const int blk = blockIdx.x;                        // 0..1023
    const int b = blk >> 7;
    const int n = ((blk & 127) << 6) | lane;
    const float* fb = features + (size_t)b * NFEAT * NPTS + n;
    const float* wbase = W1 + 3 * 64 + chunk * 16;

    float acc[16];
#pragma unroll
    for (int i = 0; i < 16; ++i) acc[i] = 0.0f;

#pragma unroll 4
    for (int cp = 0; cp < 64; ++cp) {
        float f = fb[(size_t)cp * NPTS];
        const float4* w = reinterpret_cast<const float4*>(wbase + (size_t)cp * 64);
#pragma unroll
        for (int c4 = 0; c4 < 4; ++c4) {
            float4 ww = w[c4];
            acc[c4 * 4 + 0] += f * ww.x;
            acc[c4 * 4 + 1] += f * ww.y;
            acc[c4 * 4 + 2] += f * ww.z;
            acc[c4 * 4 + 3] += f * ww.w;
        }
    }
    float* o = F1 + ((size_t)b * NPTS + n) * 64 + chunk * 16;
#pragma unroll
    for (int c4 = 0; c4 < 4; ++c4) {
        float4 v;
        v.x = acc[c4 * 4 + 0]; v.y = acc[c4 * 4 + 1];
        v.z = acc[c4 * 4 + 2]; v.w = acc[c4 * 4 + 3];
        *reinterpret_cast<float4*>(o + c4 * 4) = v;
    }
}

// ---------------------------------------------------------------------------
// Fused grouped-MLP + max-pool. EXACT R7 version (empirically best: 2048
// blocks x 256 thr, static 64KB hbuf -> 2 blocks/CU = 8 waves/CU, weights
// from global (L1/L2-cached wave-uniform loads), rolled unroll-4 c-loops.
// ---------------------------------------------------------------------------
__global__ __launch_bounds__(256) void mlp_kernel(const float* __restrict__ xyz,
                                                  const float* __restrict__ W1,
                                                  const float* __restrict__ b1,
                                                  const float* __restrict__ W2,
                                                  const float* __restrict__ b2,
                                                  const float* __restrict__ W3,
                                                  const float* __restrict__ b3,
                                                  const float* __restrict__ F1,
                                                  const int* __restrict__ ballidx,
                                                  const float* __restrict__ newxyz,
                                                  float* __restrict__ outF) {
    __shared__ float hbuf[64][256];                    // 64KB static
    const int tid = threadIdx.x;
    const int k = tid & 31;
    const int sIdx = blockIdx.x * 8 + (tid >> 5);      // 0 .. BATCH*NPOINT-1
    const int b = sIdx >> 11;
    const int s = sIdx & (NPOINT - 1);

    const int p = ballidx[(size_t)sIdx * NSAMPLE + k];
    const float* xb = xyz + (size_t)b * NPTS * 3;
    float rx = xb[p * 3 + 0] - newxyz[(size_t)sIdx * 3 + 0];
    float ry = xb[p * 3 + 1] - newxyz[(size_t)sIdx * 3 + 1];
    float rz = xb[p * 3 + 2] - newxyz[(size_t)sIdx * 3 + 2];

    // ---- layer 1 -> LDS column
    const float* f1p = F1 + ((size_t)b * NPTS + p) * 64;
#pragma unroll 4
    for (int c4 = 0; c4 < 16; ++c4) {
        float4 f  = *reinterpret_cast<const float4*>(f1p + c4 * 4);
        float4 wx = *reinterpret_cast<const float4*>(W1 + c4 * 4);
        float4 wy = *reinterpret_cast<const float4*>(W1 + 64 + c4 * 4);
        float4 wz = *reinterpret_cast<const float4*>(W1 + 128 + c4 * 4);
        float4 bb = *reinterpret_cast<const float4*>(b1 + c4 * 4);
        hbuf[c4 * 4 + 0][tid] = fmaxf(bb.x + f.x + rx * wx.x + ry * wy.x + rz * wz.x, 0.0f);
        hbuf[c4 * 4 + 1][tid] = fmaxf(bb.y + f.y + rx * wx.y + ry * wy.y + rz * wz.y, 0.0f);
        hbuf[c4 * 4 + 2][tid] = fmaxf(bb.z + f.z + rx * wx.z + ry * wy.z + rz * wz.z, 0.0f);
        hbuf[c4 * 4 + 3][tid] = fmaxf(bb.w + f.w + rx * wx.w + ry * wy.w + rz * wz.w, 0.0f);
    }

    // ---- layer 2: h2 in regs, h1 read from LDS
    float h2[64];
#pragma unroll
    for (int d4 = 0; d4 < 16; ++d4) {
        float4 bb = *reinterpret_cast<const float4*>(b2 + d4 * 4);
        h2[d4 * 4 + 0] = bb.x; h2[d4 * 4 + 1] = bb.y;
        h2[d4 * 4 + 2] = bb.z; h2[d4 * 4 + 3] = bb.w;
    }
#pragma unroll 4
    for (int c = 0; c < 64; ++c) {
        float a = hbuf[c][tid];
        const float4* w = reinterpret_cast<const float4*>(W2 + (size_t)c * 64);
#pragma unroll
        for (int d4 = 0; d4 < 16; ++d4) {
            float4 ww = w[d4];
            h2[d4 * 4 + 0] += a * ww.x;
            h2[d4 * 4 + 1] += a * ww.y;
            h2[d4 * 4 + 2] += a * ww.z;
            h2[d4 * 4 + 3] += a * ww.w;
        }
    }
    // relu + restage into same LDS columns (h1 dead; own column -> no barrier)
#pragma unroll
    for (int d = 0; d < 64; ++d) hbuf[d][tid] = fmaxf(h2[d], 0.0f);

    // ---- layer 3 + relu + max over 32 samples, 4 chunks of 32 channels
    const size_t obase = (size_t)b * 128 * NPOINT + s;
#pragma unroll 1
    for (int ch = 0; ch < 4; ++ch) {
        float acc[32];
#pragma unroll
        for (int j4 = 0; j4 < 8; ++j4) {
            float4 bb = *reinterpret_cast<const float4*>(b3 + ch * 32 + j4 * 4);
            acc[j4 * 4 + 0] = bb.x; acc[j4 * 4 + 1] = bb.y;
            acc[j4 * 4 + 2] = bb.z; acc[j4 * 4 + 3] = bb.w;
        }
#pragma unroll 4
        for (int c = 0; c < 64; ++c) {
            float a = hbuf[c][tid];
            const float4* w = reinterpret_cast<const float4*>(W3 + (size_t)c * 128 + ch * 32);
#pragma unroll
            for (int j4 = 0; j4 < 8; ++j4) {
                float4 ww = w[j4];
                acc[j4 * 4 + 0] += a * ww.x;
                acc[j4 * 4 + 1] += a * ww.y;
                acc[j4 * 4 + 2] += a * ww.z;
                acc[j4 * 4 + 3] += a * ww.w;
            }
        }
#pragma unroll
        for (int j = 0; j < 32; ++j) {
            float v = fmaxf(acc[j], 0.0f);
#pragma unroll
            for (int m = 16; m >= 1; m >>= 1) v = fmaxf(v, __shfl_xor(v, m, 64));
            acc[j] = v;
        }
        if (k == 0) {
#pragma unroll
            for (int j = 0; j < 32; ++j)
                outF[obase + (size_t)(ch * 32 + j) * NPOINT] = acc[j];
        }
    }
}

// ---------------------------------------------------------------------------
extern "C" void kernel_launch(void* const* d_in, const int* in_sizes, int n_in,
                              void* d_out, int out_size, void* d_ws, size_t ws_size,
                              hipStream_t stream) {
    const float* xyz      = (const float*)d_in[0];
    const float* features = (const float*)d_in[1];
    const float* W1       = (const float*)d_in[2];
    const float* b1       = (const float*)d_in[3];
    const float* W2       = (const float*)d_in[4];
    const float* b2       = (const float*)d_in[5];
    const float* W3       = (const float*)d_in[6];
    const float* b3       = (const float*)d_in[7];

    float* out_newxyz = (float*)d_out;                                  // B*NPOINT*3 f32
    float* out_feat   = (float*)d_out + (size_t)BATCH * NPOINT * 3;     // B*128*NPOINT f32

    // workspace: ballidx 2MB | F1 16.8MB
    int*   ballidx = (int*)d_ws;
    float* F1      = (float*)((char*)d_ws + (size_t)BATCH * NPOINT * NSAMPLE * 4);

    f1_kernel<<<1024, 256, 0, stream>>>(features, W1, F1);

    fps_kernel<<<BATCH, 512, NPTS * 16, stream>>>(xyz, out_newxyz);

    ball_kernel<<<dim3(NPOINT / 64, BATCH), 64, NPTS * 16, stream>>>(xyz, out_newxyz, ballidx);

    mlp_kernel<<<(BATCH * NPOINT) / 8, 256, 0, stream>>>(
        xyz, W1, b1, W2, b2, W3, b3, F1, ballidx, out_newxyz, out_feat);
}